// Round 1
// baseline (346.532 us; speedup 1.0000x reference)
//
#include <hip/hip_runtime.h>
#include <stdint.h>

typedef _Float16 f16;
typedef _Float16 half4 __attribute__((ext_vector_type(4)));
typedef _Float16 f16x8 __attribute__((ext_vector_type(8)));
typedef float f32x4 __attribute__((ext_vector_type(4)));

// ---------------- CSR build (bucketed counting sort; n <= 131072 assumed for packing) ----

#define BKT_SH 9
#define BKT_SZ 512
#define EB 4096

__global__ void k_zero_int(int* __restrict__ p, int n) {
    int i = blockIdx.x * blockDim.x + threadIdx.x;
    if (i < n) p[i] = 0;
}

__global__ __launch_bounds__(256) void k_bhist(const int* __restrict__ dst, int E, int nbk,
                                               int* __restrict__ gcnt) {
    __shared__ int h[128];
    int tid = threadIdx.x;
    if (tid < 128) h[tid] = 0;
    __syncthreads();
    int base = blockIdx.x * EB;
    int end = min(base + EB, E);
    for (int i = base + tid; i < end; i += 256) atomicAdd(&h[dst[i] >> BKT_SH], 1);
    __syncthreads();
    if (tid < nbk && h[tid]) atomicAdd(&gcnt[tid], h[tid]);
}

// binA with local re-scan of gcnt (replaces k_bscan + k_binA)
__global__ __launch_bounds__(256) void k_binA2(const int* __restrict__ src, const int* __restrict__ dst,
                                               int E, const int* __restrict__ gcnt,
                                               int* __restrict__ bcur, unsigned* __restrict__ ebuf) {
    __shared__ int h[128], segs[128], cur[128], s[256];
    int tid = threadIdx.x;
    if (tid < 128) { h[tid] = 0; cur[tid] = 0; }
    __syncthreads();
    int base = blockIdx.x * EB;
    int end = min(base + EB, E);
    for (int i = base + tid; i < end; i += 256) atomicAdd(&h[dst[i] >> BKT_SH], 1);
    // local inclusive scan of gcnt (gives bucket bases); barrier also completes the histogram
    int v = (tid < 128) ? gcnt[tid] : 0;
    s[tid] = v;
    __syncthreads();
    for (int o = 1; o < 256; o <<= 1) {
        int t = (tid >= o) ? s[tid - o] : 0;
        __syncthreads();
        s[tid] += t;
        __syncthreads();
    }
    if (tid < 128) segs[tid] = h[tid] ? (s[tid] - v) + atomicAdd(&bcur[tid], h[tid]) : 0;
    __syncthreads();
    for (int i = base + tid; i < end; i += 256) {
        int d = dst[i];
        int bk = d >> BKT_SH;
        int r = atomicAdd(&cur[bk], 1);
        ebuf[segs[bk] + r] = (unsigned)src[i] | ((unsigned)(d & (BKT_SZ - 1)) << 17);
    }
}

// csr with local re-scan of gcnt (no bbase input); also writes row_ptr[n] = E
__global__ __launch_bounds__(256) void k_csr2(const unsigned* __restrict__ ebuf,
                                              const int* __restrict__ gcnt,
                                              int n, int E, int* __restrict__ row_ptr,
                                              float* __restrict__ dinv, int* __restrict__ ssorted) {
    __shared__ int cnt[BKT_SZ], exc[BKT_SZ], cur2[BKT_SZ], p[256];
    int b = blockIdx.x, tid = threadIdx.x;
    // local inclusive scan of gcnt -> bucket base s0
    int v = (tid < 128) ? gcnt[tid] : 0;
    p[tid] = v;
    __syncthreads();
    for (int o = 1; o < 256; o <<= 1) {
        int t = (tid >= o) ? p[tid - o] : 0;
        __syncthreads();
        p[tid] += t;
        __syncthreads();
    }
    int scnt = gcnt[b];
    int s0 = p[b] - scnt;
    __syncthreads();
    if (b == 0 && tid == 0) row_ptr[n] = E;

    int d0 = b << BKT_SH;
    int ndl = min(BKT_SZ, n - d0);
    cnt[tid] = 0; cnt[tid + 256] = 0;
    cur2[tid] = 0; cur2[tid + 256] = 0;
    __syncthreads();
    for (int i = tid; i < scnt; i += 256)
        atomicAdd(&cnt[(ebuf[s0 + i] >> 17) & (BKT_SZ - 1)], 1);
    __syncthreads();
    int a = cnt[2 * tid], c2 = cnt[2 * tid + 1];
    p[tid] = a + c2;
    __syncthreads();
    for (int o = 1; o < 256; o <<= 1) {
        int t = (tid >= o) ? p[tid - o] : 0;
        __syncthreads();
        p[tid] += t;
        __syncthreads();
    }
    int pex = p[tid] - (a + c2);
    exc[2 * tid] = pex;
    exc[2 * tid + 1] = pex + a;
    __syncthreads();
    for (int dl = tid; dl < ndl; dl += 256) {
        row_ptr[d0 + dl] = s0 + exc[dl];
        dinv[d0 + dl] = rsqrtf((float)(cnt[dl] + 1));  // +1 self loop
    }
    for (int i = tid; i < scnt; i += 256) {
        unsigned e = ebuf[s0 + i];
        int dl = (e >> 17) & (BKT_SZ - 1);
        int r = atomicAdd(&cur2[dl], 1);
        ssorted[s0 + exc[dl] + r] = (int)(e & 0x1FFFF);
    }
}

// ---------------- GEMM1 (MFMA): h1_pre[n,64] = x[n,256] @ W_enc_gnn[256,64] -> f16 ------

#define G1M_R 64
__global__ __launch_bounds__(256) void k_gemm1(const float* __restrict__ x,
                                               const float* __restrict__ W,
                                               f16* __restrict__ out, int n) {
    __shared__ __attribute__((aligned(16))) f16 WB[4 * 8 * 64 * 8];  // 32 KB
    __shared__ __attribute__((aligned(16))) f16 Ah[64 * 136];        // 17 KB
    int tid = threadIdx.x;
    int row0 = blockIdx.x * G1M_R;

    for (int i = tid; i < 4096; i += 256) {
        int k = i >> 4, c4 = (i & 15) * 4;
        float4 w = *(const float4*)&W[k * 64 + c4];
        int t = c4 >> 4, ks = k >> 5, q = (k & 31) >> 3, j = k & 7;
        int base = (((t * 8 + ks) * 64 + q * 16 + (c4 & 15)) * 8) + j;
        WB[base + 0]  = (f16)w.x;
        WB[base + 8]  = (f16)w.y;
        WB[base + 16] = (f16)w.z;
        WB[base + 24] = (f16)w.w;
    }

    int lane = tid & 63, w = tid >> 6;
    int m = lane & 15, q = lane >> 4;

    f32x4 acc[4];
#pragma unroll
    for (int t = 0; t < 4; t++) acc[t] = (f32x4){0.f, 0.f, 0.f, 0.f};

    for (int h = 0; h < 2; h++) {
        __syncthreads();
        for (int i = tid; i < 2048; i += 256) {
            int r = i >> 5, k4 = (i & 31) * 4;
            float4 v = {0.f, 0.f, 0.f, 0.f};
            if (row0 + r < n) v = *(const float4*)&x[(size_t)(row0 + r) * 256 + 128 * h + k4];
            half4 hv;
            hv.x = (f16)v.x; hv.y = (f16)v.y; hv.z = (f16)v.z; hv.w = (f16)v.w;
            *(half4*)&Ah[r * 136 + k4] = hv;
        }
        __syncthreads();
#pragma unroll
        for (int ksl = 0; ksl < 4; ksl++) {
            int ks = 4 * h + ksl;
            f16x8 a = *(const f16x8*)&Ah[(16 * w + m) * 136 + 32 * ksl + 8 * q];
#pragma unroll
            for (int t = 0; t < 4; t++) {
                f16x8 b = *(const f16x8*)&WB[((t * 8 + ks) * 64 + lane) * 8];
                acc[t] = __builtin_amdgcn_mfma_f32_16x16x32_f16(a, b, acc[t], 0, 0, 0);
            }
        }
    }

#pragma unroll
    for (int t = 0; t < 4; t++) {
#pragma unroll
        for (int r = 0; r < 4; r++) {
            int gr = row0 + 16 * w + 4 * q + r;
            if (gr < n) out[(size_t)gr * 64 + 16 * t + m] = (f16)acc[t][r];
        }
    }
}

// ---------------- shared gather helper: returns dinv[d]*(sum_s dinv[s]*h[s] + dinv[d]*h[d])

__device__ __forceinline__ float gcn_gather(const f16* __restrict__ hpre,
                                            const int* __restrict__ row_ptr,
                                            const int* __restrict__ ssorted,
                                            const float* __restrict__ dinv,
                                            int d, int lane) {
    float dd = dinv[d];
    float acc = dd * (float)hpre[(size_t)d * 64 + lane];  // self loop
    int s0 = row_ptr[d], s1 = row_ptr[d + 1];
    for (int base = s0; base < s1; base += 64) {
        int j = base + lane;
        int sl = 0;
        float wl = 0.f;
        if (j < s1) { sl = ssorted[j]; wl = dinv[sl]; }
        int cnt = min(64, s1 - base);
        int i = 0;
        for (; i + 4 <= cnt; i += 4) {
            int a0 = __shfl(sl, i), a1 = __shfl(sl, i + 1);
            int a2 = __shfl(sl, i + 2), a3 = __shfl(sl, i + 3);
            float w0 = __shfl(wl, i), w1 = __shfl(wl, i + 1);
            float w2 = __shfl(wl, i + 2), w3 = __shfl(wl, i + 3);
            float v0 = (float)hpre[(size_t)a0 * 64 + lane];
            float v1 = (float)hpre[(size_t)a1 * 64 + lane];
            float v2 = (float)hpre[(size_t)a2 * 64 + lane];
            float v3 = (float)hpre[(size_t)a3 * 64 + lane];
            acc += w0 * v0; acc += w1 * v1; acc += w2 * v2; acc += w3 * v3;
        }
        for (; i < cnt; i++) {
            int a = __shfl(sl, i);
            float w = __shfl(wl, i);
            acc += w * (float)hpre[(size_t)a * 64 + lane];
        }
    }
    return dd * acc;
}

// ---------------- fused prop1 + middle (MFMA): 64 nodes per block --------------------
// Ah = relu(P(h1pre) + b_enc)  computed in-block, then z / hd / pred as before.

#define MB 64
__global__ __launch_bounds__(256) void k_mid_f(const f16* __restrict__ h1pre,
                                               const int* __restrict__ row_ptr,
                                               const int* __restrict__ ssorted,
                                               const float* __restrict__ dinv,
                                               const float* __restrict__ benc,
                                               const float* __restrict__ Wz, const float* __restrict__ bz,
                                               const float* __restrict__ Wd, const float* __restrict__ bd,
                                               const float* __restrict__ Wc, const float* __restrict__ bc,
                                               f16* __restrict__ hd_ws,
                                               float* __restrict__ z_out, float* __restrict__ pred_out,
                                               int n) {
    __shared__ __attribute__((aligned(16))) f16 Ah[64 * 72];
    __shared__ __attribute__((aligned(16))) f16 Zh[64 * 40];
    __shared__ __attribute__((aligned(16))) f16 WzB[2 * 2 * 64 * 8];
    __shared__ __attribute__((aligned(16))) f16 WdB[4 * 64 * 8];
    __shared__ float Wcs[32 * 4];
    __shared__ float bzs[32], bds[64], bcs[4], bes[64];
    int tid = threadIdx.x;
    int row0 = blockIdx.x * MB;

    for (int i = tid; i < 2048; i += 256) {
        int k = i >> 5, c = i & 31;
        int ks = k >> 5, q = (k >> 3) & 3, j = k & 7;
        int t = c >> 4, ln = q * 16 + (c & 15);
        WzB[((t * 2 + ks) * 64 + ln) * 8 + j] = (f16)Wz[i];
    }
    for (int i = tid; i < 2048; i += 256) {
        int k = i >> 6, c = i & 63;
        int q = k >> 3, j = k & 7;
        int t = c >> 4, ln = q * 16 + (c & 15);
        WdB[(t * 64 + ln) * 8 + j] = (f16)Wd[i];
    }
    if (tid < 96) Wcs[(tid / 3) * 4 + (tid % 3)] = Wc[tid];
    if (tid < 32) bzs[tid] = bz[tid];
    if (tid < 64) bds[tid] = bd[tid];
    if (tid < 3)  bcs[tid] = bc[tid];
    if (tid < 64) bes[tid] = benc[tid];
    __syncthreads();

    int lane = tid & 63, wid = tid >> 6;

    // prop phase: each wave computes 16 rows of Ah = relu(P(h1pre) + b_enc), f16
    for (int no = wid; no < MB; no += 4) {
        int d = row0 + no;
        float val = 0.f;
        if (d < n)
            val = fmaxf(gcn_gather(h1pre, row_ptr, ssorted, dinv, d, lane) + bes[lane], 0.f);
        Ah[no * 72 + lane] = (f16)val;
    }
    __syncthreads();

    int m = lane & 15, q = lane >> 4;

    f32x4 za[2];
    za[0] = (f32x4){0.f, 0.f, 0.f, 0.f};
    za[1] = (f32x4){0.f, 0.f, 0.f, 0.f};
#pragma unroll
    for (int ks = 0; ks < 2; ks++) {
        f16x8 a = *(const f16x8*)&Ah[(16 * wid + m) * 72 + 32 * ks + 8 * q];
#pragma unroll
        for (int t = 0; t < 2; t++) {
            f16x8 b = *(const f16x8*)&WzB[((t * 2 + ks) * 64 + lane) * 8];
            za[t] = __builtin_amdgcn_mfma_f32_16x16x32_f16(a, b, za[t], 0, 0, 0);
        }
    }
#pragma unroll
    for (int t = 0; t < 2; t++) {
        float bj = bzs[16 * t + m];
#pragma unroll
        for (int r = 0; r < 4; r++) {
            int node = 16 * wid + 4 * q + r;
            float zv = za[t][r] + bj;
            Zh[node * 40 + 16 * t + m] = (f16)zv;
            if (row0 + node < n) z_out[(size_t)(row0 + node) * 32 + 16 * t + m] = zv;
        }
    }
    __syncthreads();

    f16x8 a2 = *(const f16x8*)&Zh[(16 * wid + m) * 40 + 8 * q];
    f32x4 hb[4];
#pragma unroll
    for (int t = 0; t < 4; t++) {
        f16x8 b = *(const f16x8*)&WdB[(t * 64 + lane) * 8];
        f32x4 zero = (f32x4){0.f, 0.f, 0.f, 0.f};
        hb[t] = __builtin_amdgcn_mfma_f32_16x16x32_f16(a2, b, zero, 0, 0, 0);
    }
#pragma unroll
    for (int t = 0; t < 4; t++) {
        float bf = bds[16 * t + m];
#pragma unroll
        for (int r = 0; r < 4; r++) {
            int node = 16 * wid + 4 * q + r;
            if (row0 + node < n)
                hd_ws[(size_t)(row0 + node) * 64 + 16 * t + m] = (f16)fmaxf(hb[t][r] + bf, 0.f);
        }
    }

    if (tid < 64) {
        int node = tid;
        float pa = bcs[0], pb = bcs[1], pc = bcs[2];
        for (int k = 0; k < 32; k++) {
            float zv = (float)Zh[node * 40 + k];
            pa += zv * Wcs[k * 4 + 0];
            pb += zv * Wcs[k * 4 + 1];
            pc += zv * Wcs[k * 4 + 2];
        }
        if (row0 + node < n) {
            pred_out[(size_t)(row0 + node) * 3 + 0] = pa;
            pred_out[(size_t)(row0 + node) * 3 + 1] = pb;
            pred_out[(size_t)(row0 + node) * 3 + 2] = pc;
        }
    }
}

// ---------------- fused prop2 + GEMM5 (MFMA): x_recon = (P hd)[64 rows] @ W_dec + b -----

#define G5_R 64
__global__ __launch_bounds__(256) void k_dec_f(const f16* __restrict__ hd,
                                               const int* __restrict__ row_ptr,
                                               const int* __restrict__ ssorted,
                                               const float* __restrict__ dinv,
                                               const float* __restrict__ W,
                                               const float* __restrict__ bias,
                                               float* __restrict__ out, int n) {
    __shared__ __attribute__((aligned(16))) f16 WB[16 * 2 * 64 * 8];  // 32 KB
    __shared__ __attribute__((aligned(16))) f16 Ah[64 * 72];          // 9 KB
    __shared__ float bs[256];
    int tid = threadIdx.x;
    int row0 = blockIdx.x * G5_R;

    for (int i = tid; i < 4096; i += 256) {
        int k = i >> 6, c4 = (i & 63) * 4;
        float4 w = *(const float4*)&W[k * 256 + c4];
        int ks = k >> 5, q = (k >> 3) & 3, j = k & 7;
        int t = c4 >> 4;
        int base = ((t * 2 + ks) * 64 + q * 16 + (c4 & 15)) * 8 + j;
        WB[base + 0]  = (f16)w.x;
        WB[base + 8]  = (f16)w.y;
        WB[base + 16] = (f16)w.z;
        WB[base + 24] = (f16)w.w;
    }
    bs[tid] = bias[tid];

    int lane = tid & 63, wid = tid >> 6;

    // prop phase: each wave computes 16 rows of Ah = P(hd), f16
    for (int no = wid; no < G5_R; no += 4) {
        int d = row0 + no;
        float val = 0.f;
        if (d < n) val = gcn_gather(hd, row_ptr, ssorted, dinv, d, lane);
        Ah[no * 72 + lane] = (f16)val;
    }
    __syncthreads();

    int m = lane & 15, q = lane >> 4;

    f16x8 a0 = *(const f16x8*)&Ah[(16 * wid + m) * 72 + 0 + 8 * q];
    f16x8 a1 = *(const f16x8*)&Ah[(16 * wid + m) * 72 + 32 + 8 * q];

    int gr0 = row0 + 16 * wid + 4 * q;
    bool full = (gr0 + 3 < n);
#pragma unroll 4
    for (int t = 0; t < 16; t++) {
        f32x4 acc = (f32x4){0.f, 0.f, 0.f, 0.f};
        f16x8 b0 = *(const f16x8*)&WB[((t * 2 + 0) * 64 + lane) * 8];
        acc = __builtin_amdgcn_mfma_f32_16x16x32_f16(a0, b0, acc, 0, 0, 0);
        f16x8 b1 = *(const f16x8*)&WB[((t * 2 + 1) * 64 + lane) * 8];
        acc = __builtin_amdgcn_mfma_f32_16x16x32_f16(a1, b1, acc, 0, 0, 0);
        float bf = bs[16 * t + m];
        if (full) {
#pragma unroll
            for (int r = 0; r < 4; r++)
                out[(size_t)(gr0 + r) * 256 + 16 * t + m] = acc[r] + bf;
        } else {
#pragma unroll
            for (int r = 0; r < 4; r++)
                if (gr0 + r < n) out[(size_t)(gr0 + r) * 256 + 16 * t + m] = acc[r] + bf;
        }
    }
}

// ---------------- launch ----------------

extern "C" void kernel_launch(void* const* d_in, const int* in_sizes, int n_in,
                              void* d_out, int out_size, void* d_ws, size_t ws_size,
                              hipStream_t stream) {
    const float* x    = (const float*)d_in[0];
    const int*   ei   = (const int*)d_in[1];
    const float* Wenc = (const float*)d_in[3];
    const float* benc = (const float*)d_in[4];
    const float* Wz   = (const float*)d_in[5];
    const float* bz   = (const float*)d_in[6];
    const float* Wd   = (const float*)d_in[7];
    const float* bd   = (const float*)d_in[8];
    const float* Wdec = (const float*)d_in[9];
    const float* bdec = (const float*)d_in[10];
    const float* Wc   = (const float*)d_in[11];
    const float* bc   = (const float*)d_in[12];

    int n = in_sizes[0] / 256;
    int E = in_sizes[1] / 2;
    const int* src = ei;
    const int* dst = ei + E;

    int nbk = (n + BKT_SZ - 1) >> BKT_SH;
    int nbin = (E + EB - 1) / EB;

    char* w = (char*)d_ws;
    size_t off = 0;
    auto alloc = [&](size_t bytes) {
        void* p = w + off;
        off = (off + bytes + 255) & ~(size_t)255;
        return p;
    };
    int*      row_ptr = (int*)alloc(sizeof(int) * (n + 1));
    int*      ssorted = (int*)alloc(sizeof(int) * E);
    unsigned* ebuf    = (unsigned*)alloc(sizeof(unsigned) * E);
    float*    dinv    = (float*)alloc(sizeof(float) * n);
    int*      cnts    = (int*)alloc(sizeof(int) * 256);  // gcnt[128] + bcur[128]
    f16*      bufA    = (f16*)alloc(sizeof(f16) * (size_t)n * 64);  // h1pre
    f16*      bufB    = (f16*)alloc(sizeof(f16) * (size_t)n * 64);  // hd
    (void)ws_size; (void)n_in; (void)out_size;

    int* gcnt = cnts;
    int* bcur = cnts + 128;

    float* out_xr = (float*)d_out;
    float* out_z  = out_xr + (size_t)n * 256;
    float* out_p  = out_z + (size_t)n * 32;

    // CSR build (bucketed counting sort) — 4 dispatches
    k_zero_int<<<dim3(1), dim3(256), 0, stream>>>(cnts, 256);
    k_bhist<<<dim3(nbin), dim3(256), 0, stream>>>(dst, E, nbk, gcnt);
    k_binA2<<<dim3(nbin), dim3(256), 0, stream>>>(src, dst, E, gcnt, bcur, ebuf);
    k_csr2<<<dim3(nbk), dim3(256), 0, stream>>>(ebuf, gcnt, n, E, row_ptr, dinv, ssorted);

    // encoder GEMM: bufA = x @ W_enc (f16)
    k_gemm1<<<dim3((n + G1M_R - 1) / G1M_R), dim3(256), 0, stream>>>(x, Wenc, bufA, n);

    // fused prop1 + middle: z (out), pred (out), hd -> bufB (f16)
    k_mid_f<<<dim3((n + MB - 1) / MB), dim3(256), 0, stream>>>(bufA, row_ptr, ssorted, dinv, benc,
                                                               Wz, bz, Wd, bd, Wc, bc,
                                                               bufB, out_z, out_p, n);

    // fused prop2 + decoder GEMM: x_recon = P(bufB) @ W_dec + b_dec
    k_dec_f<<<dim3((n + G5_R - 1) / G5_R), dim3(256), 0, stream>>>(bufB, row_ptr, ssorted, dinv,
                                                                   Wdec, bdec, out_xr, n);
}

// Round 2
// 274.985 us; speedup vs baseline: 1.2602x; 1.2602x over previous
//
#include <hip/hip_runtime.h>
#include <stdint.h>

typedef _Float16 f16;
typedef _Float16 half4 __attribute__((ext_vector_type(4)));
typedef _Float16 f16x8 __attribute__((ext_vector_type(8)));
typedef float f32x4 __attribute__((ext_vector_type(4)));

// ---------------- CSR build (bucketed counting sort; n <= 131072 assumed for packing) ----

#define BKT_SH 9
#define BKT_SZ 512
#define EB 4096

__global__ void k_zero_int(int* __restrict__ p, int n) {
    int i = blockIdx.x * blockDim.x + threadIdx.x;
    if (i < n) p[i] = 0;
}

__global__ __launch_bounds__(256) void k_bhist(const int* __restrict__ dst, int E, int nbk,
                                               int* __restrict__ gcnt) {
    __shared__ int h[128];
    int tid = threadIdx.x;
    if (tid < 128) h[tid] = 0;
    __syncthreads();
    int base = blockIdx.x * EB;
    int end = min(base + EB, E);
    for (int i = base + tid; i < end; i += 256) atomicAdd(&h[dst[i] >> BKT_SH], 1);
    __syncthreads();
    if (tid < nbk && h[tid]) atomicAdd(&gcnt[tid], h[tid]);
}

// binA with local re-scan of gcnt (no separate scan kernel)
__global__ __launch_bounds__(256) void k_binA2(const int* __restrict__ src, const int* __restrict__ dst,
                                               int E, const int* __restrict__ gcnt,
                                               int* __restrict__ bcur, unsigned* __restrict__ ebuf) {
    __shared__ int h[128], segs[128], cur[128], s[256];
    int tid = threadIdx.x;
    if (tid < 128) { h[tid] = 0; cur[tid] = 0; }
    __syncthreads();
    int base = blockIdx.x * EB;
    int end = min(base + EB, E);
    for (int i = base + tid; i < end; i += 256) atomicAdd(&h[dst[i] >> BKT_SH], 1);
    int v = (tid < 128) ? gcnt[tid] : 0;
    s[tid] = v;
    __syncthreads();
    for (int o = 1; o < 256; o <<= 1) {
        int t = (tid >= o) ? s[tid - o] : 0;
        __syncthreads();
        s[tid] += t;
        __syncthreads();
    }
    if (tid < 128) segs[tid] = h[tid] ? (s[tid] - v) + atomicAdd(&bcur[tid], h[tid]) : 0;
    __syncthreads();
    for (int i = base + tid; i < end; i += 256) {
        int d = dst[i];
        int bk = d >> BKT_SH;
        int r = atomicAdd(&cur[bk], 1);
        ebuf[segs[bk] + r] = (unsigned)src[i] | ((unsigned)(d & (BKT_SZ - 1)) << 17);
    }
}

// csr with local re-scan of gcnt; also writes row_ptr[n] = E
__global__ __launch_bounds__(256) void k_csr2(const unsigned* __restrict__ ebuf,
                                              const int* __restrict__ gcnt,
                                              int n, int E, int* __restrict__ row_ptr,
                                              float* __restrict__ dinv, int* __restrict__ ssorted) {
    __shared__ int cnt[BKT_SZ], exc[BKT_SZ], cur2[BKT_SZ], p[256];
    int b = blockIdx.x, tid = threadIdx.x;
    int v = (tid < 128) ? gcnt[tid] : 0;
    p[tid] = v;
    __syncthreads();
    for (int o = 1; o < 256; o <<= 1) {
        int t = (tid >= o) ? p[tid - o] : 0;
        __syncthreads();
        p[tid] += t;
        __syncthreads();
    }
    int scnt = gcnt[b];
    int s0 = p[b] - scnt;
    __syncthreads();
    if (b == 0 && tid == 0) row_ptr[n] = E;

    int d0 = b << BKT_SH;
    int ndl = min(BKT_SZ, n - d0);
    cnt[tid] = 0; cnt[tid + 256] = 0;
    cur2[tid] = 0; cur2[tid + 256] = 0;
    __syncthreads();
    for (int i = tid; i < scnt; i += 256)
        atomicAdd(&cnt[(ebuf[s0 + i] >> 17) & (BKT_SZ - 1)], 1);
    __syncthreads();
    int a = cnt[2 * tid], c2 = cnt[2 * tid + 1];
    p[tid] = a + c2;
    __syncthreads();
    for (int o = 1; o < 256; o <<= 1) {
        int t = (tid >= o) ? p[tid - o] : 0;
        __syncthreads();
        p[tid] += t;
        __syncthreads();
    }
    int pex = p[tid] - (a + c2);
    exc[2 * tid] = pex;
    exc[2 * tid + 1] = pex + a;
    __syncthreads();
    for (int dl = tid; dl < ndl; dl += 256) {
        row_ptr[d0 + dl] = s0 + exc[dl];
        dinv[d0 + dl] = rsqrtf((float)(cnt[dl] + 1));  // +1 self loop
    }
    for (int i = tid; i < scnt; i += 256) {
        unsigned e = ebuf[s0 + i];
        int dl = (e >> 17) & (BKT_SZ - 1);
        int r = atomicAdd(&cur2[dl], 1);
        ssorted[s0 + exc[dl] + r] = (int)(e & 0x1FFFF);
    }
}

// ---------------- GEMM1 (MFMA): h1_pre[n,64] = x[n,256] @ W_enc_gnn[256,64] -> f16 ------

#define G1M_R 64
__global__ __launch_bounds__(256) void k_gemm1(const float* __restrict__ x,
                                               const float* __restrict__ W,
                                               f16* __restrict__ out, int n) {
    __shared__ __attribute__((aligned(16))) f16 WB[4 * 8 * 64 * 8];  // 32 KB
    __shared__ __attribute__((aligned(16))) f16 Ah[64 * 136];        // 17 KB
    int tid = threadIdx.x;
    int row0 = blockIdx.x * G1M_R;

    for (int i = tid; i < 4096; i += 256) {
        int k = i >> 4, c4 = (i & 15) * 4;
        float4 w = *(const float4*)&W[k * 64 + c4];
        int t = c4 >> 4, ks = k >> 5, q = (k & 31) >> 3, j = k & 7;
        int base = (((t * 8 + ks) * 64 + q * 16 + (c4 & 15)) * 8) + j;
        WB[base + 0]  = (f16)w.x;
        WB[base + 8]  = (f16)w.y;
        WB[base + 16] = (f16)w.z;
        WB[base + 24] = (f16)w.w;
    }

    int lane = tid & 63, w = tid >> 6;
    int m = lane & 15, q = lane >> 4;

    f32x4 acc[4];
#pragma unroll
    for (int t = 0; t < 4; t++) acc[t] = (f32x4){0.f, 0.f, 0.f, 0.f};

    for (int h = 0; h < 2; h++) {
        __syncthreads();
        for (int i = tid; i < 2048; i += 256) {
            int r = i >> 5, k4 = (i & 31) * 4;
            float4 v = {0.f, 0.f, 0.f, 0.f};
            if (row0 + r < n) v = *(const float4*)&x[(size_t)(row0 + r) * 256 + 128 * h + k4];
            half4 hv;
            hv.x = (f16)v.x; hv.y = (f16)v.y; hv.z = (f16)v.z; hv.w = (f16)v.w;
            *(half4*)&Ah[r * 136 + k4] = hv;
        }
        __syncthreads();
#pragma unroll
        for (int ksl = 0; ksl < 4; ksl++) {
            int ks = 4 * h + ksl;
            f16x8 a = *(const f16x8*)&Ah[(16 * w + m) * 136 + 32 * ksl + 8 * q];
#pragma unroll
            for (int t = 0; t < 4; t++) {
                f16x8 b = *(const f16x8*)&WB[((t * 8 + ks) * 64 + lane) * 8];
                acc[t] = __builtin_amdgcn_mfma_f32_16x16x32_f16(a, b, acc[t], 0, 0, 0);
            }
        }
    }

#pragma unroll
    for (int t = 0; t < 4; t++) {
#pragma unroll
        for (int r = 0; r < 4; r++) {
            int gr = row0 + 16 * w + 4 * q + r;
            if (gr < n) out[(size_t)gr * 64 + 16 * t + m] = (f16)acc[t][r];
        }
    }
}

// ---------------- propagation (f16 in/out): out[d] = dinv[d]*(sum dinv[s]*h[s] + dinv[d]*h[d])
// wave layout: 4 edge-subgroups (eg = lane>>4) x 16 feature-lanes (fg = lane&15).
// Each lane loads half4 (8B) -> one wave-load fetches 4 full edge rows (512B).

template <bool RELU_BIAS>
__global__ __launch_bounds__(256) void k_prop(const f16* __restrict__ hpre,
                                              const int* __restrict__ row_ptr,
                                              const int* __restrict__ ssorted,
                                              const float* __restrict__ dinv,
                                              const float* __restrict__ bias,
                                              f16* __restrict__ out, int n) {
    int lane = threadIdx.x & 63, wid = threadIdx.x >> 6;
    int d = blockIdx.x * 4 + wid;
    if (d >= n) return;
    int fg = lane & 15;   // features 4*fg .. 4*fg+3
    int eg = lane >> 4;   // edge subgroup 0..3
    float dd = dinv[d];

    float ax = 0.f, ay = 0.f, az = 0.f, aw = 0.f;
    if (eg == 0) {  // self loop only in subgroup 0
        half4 hv = *(const half4*)&hpre[(size_t)d * 64 + 4 * fg];
        ax = dd * (float)hv.x; ay = dd * (float)hv.y;
        az = dd * (float)hv.z; aw = dd * (float)hv.w;
    }

    int s0 = row_ptr[d], s1 = row_ptr[d + 1];
    for (int base = s0; base < s1; base += 64) {
        int j = base + lane;
        int sl = 0;
        float wl = 0.f;
        if (j < s1) { sl = ssorted[j]; wl = dinv[sl]; }
        int cnt = min(64, s1 - base);
        int i = 0;
        for (; i + 8 <= cnt; i += 8) {  // 8 edges per iter, 2 independent loads/lane
            int e0 = i + eg, e1 = i + 4 + eg;
            int a0 = __shfl(sl, e0), a1 = __shfl(sl, e1);
            float w0 = __shfl(wl, e0), w1 = __shfl(wl, e1);
            half4 h0 = *(const half4*)&hpre[(size_t)a0 * 64 + 4 * fg];
            half4 h1 = *(const half4*)&hpre[(size_t)a1 * 64 + 4 * fg];
            ax += w0 * (float)h0.x; ay += w0 * (float)h0.y;
            az += w0 * (float)h0.z; aw += w0 * (float)h0.w;
            ax += w1 * (float)h1.x; ay += w1 * (float)h1.y;
            az += w1 * (float)h1.z; aw += w1 * (float)h1.w;
        }
        for (; i < cnt; i += 4) {  // tail: up to 4 edges, predicated
            int e = i + eg;
            int a = __shfl(sl, e);
            float w = __shfl(wl, e);
            if (e < cnt) {
                half4 hv = *(const half4*)&hpre[(size_t)a * 64 + 4 * fg];
                ax += w * (float)hv.x; ay += w * (float)hv.y;
                az += w * (float)hv.z; aw += w * (float)hv.w;
            }
        }
    }

    // reduce the 4 edge subgroups (lanes differ in bits 4 and 5)
    ax += __shfl_xor(ax, 16); ay += __shfl_xor(ay, 16);
    az += __shfl_xor(az, 16); aw += __shfl_xor(aw, 16);
    ax += __shfl_xor(ax, 32); ay += __shfl_xor(ay, 32);
    az += __shfl_xor(az, 32); aw += __shfl_xor(aw, 32);

    if (lane < 16) {
        float vx = dd * ax, vy = dd * ay, vz = dd * az, vw = dd * aw;
        if (RELU_BIAS) {
            float4 b = *(const float4*)&bias[4 * fg];
            vx = fmaxf(vx + b.x, 0.f); vy = fmaxf(vy + b.y, 0.f);
            vz = fmaxf(vz + b.z, 0.f); vw = fmaxf(vw + b.w, 0.f);
        }
        half4 hv;
        hv.x = (f16)vx; hv.y = (f16)vy; hv.z = (f16)vz; hv.w = (f16)vw;
        *(half4*)&out[(size_t)d * 64 + 4 * fg] = hv;
    }
}

// ---------------- fused middle (MFMA): 64 nodes per block; h1/hd are f16 ----------------

#define MB 64
__global__ __launch_bounds__(256) void k_mid(const f16* __restrict__ h1,
                                             const float* __restrict__ Wz, const float* __restrict__ bz,
                                             const float* __restrict__ Wd, const float* __restrict__ bd,
                                             const float* __restrict__ Wc, const float* __restrict__ bc,
                                             f16* __restrict__ hd_ws,
                                             float* __restrict__ z_out, float* __restrict__ pred_out,
                                             int n) {
    __shared__ __attribute__((aligned(16))) f16 Ah[64 * 72];
    __shared__ __attribute__((aligned(16))) f16 Zh[64 * 40];
    __shared__ __attribute__((aligned(16))) f16 WzB[2 * 2 * 64 * 8];
    __shared__ __attribute__((aligned(16))) f16 WdB[4 * 64 * 8];
    __shared__ float Wcs[32 * 4];
    __shared__ float bzs[32], bds[64], bcs[4];
    int tid = threadIdx.x;
    int row0 = blockIdx.x * MB;

    for (int i = tid; i < 2048; i += 256) {
        int k = i >> 5, c = i & 31;
        int ks = k >> 5, q = (k >> 3) & 3, j = k & 7;
        int t = c >> 4, ln = q * 16 + (c & 15);
        WzB[((t * 2 + ks) * 64 + ln) * 8 + j] = (f16)Wz[i];
    }
    for (int i = tid; i < 2048; i += 256) {
        int k = i >> 6, c = i & 63;
        int q = k >> 3, j = k & 7;
        int t = c >> 4, ln = q * 16 + (c & 15);
        WdB[(t * 64 + ln) * 8 + j] = (f16)Wd[i];
    }
    if (tid < 96) Wcs[(tid / 3) * 4 + (tid % 3)] = Wc[tid];
    if (tid < 32) bzs[tid] = bz[tid];
    if (tid < 64) bds[tid] = bd[tid];
    if (tid < 3)  bcs[tid] = bc[tid];
    for (int i = tid; i < 1024; i += 256) {
        int r = i >> 4, c4 = (i & 15) * 4;
        half4 hv = {0, 0, 0, 0};
        if (row0 + r < n) hv = *(const half4*)&h1[(size_t)(row0 + r) * 64 + c4];
        *(half4*)&Ah[r * 72 + c4] = hv;
    }
    __syncthreads();

    int lane = tid & 63, w = tid >> 6;
    int m = lane & 15, q = lane >> 4;

    f32x4 za[2];
    za[0] = (f32x4){0.f, 0.f, 0.f, 0.f};
    za[1] = (f32x4){0.f, 0.f, 0.f, 0.f};
#pragma unroll
    for (int ks = 0; ks < 2; ks++) {
        f16x8 a = *(const f16x8*)&Ah[(16 * w + m) * 72 + 32 * ks + 8 * q];
#pragma unroll
        for (int t = 0; t < 2; t++) {
            f16x8 b = *(const f16x8*)&WzB[((t * 2 + ks) * 64 + lane) * 8];
            za[t] = __builtin_amdgcn_mfma_f32_16x16x32_f16(a, b, za[t], 0, 0, 0);
        }
    }
#pragma unroll
    for (int t = 0; t < 2; t++) {
        float bj = bzs[16 * t + m];
#pragma unroll
        for (int r = 0; r < 4; r++) {
            int node = 16 * w + 4 * q + r;
            float zv = za[t][r] + bj;
            Zh[node * 40 + 16 * t + m] = (f16)zv;
            if (row0 + node < n) z_out[(size_t)(row0 + node) * 32 + 16 * t + m] = zv;
        }
    }
    __syncthreads();

    f16x8 a2 = *(const f16x8*)&Zh[(16 * w + m) * 40 + 8 * q];
    f32x4 hb[4];
#pragma unroll
    for (int t = 0; t < 4; t++) {
        f16x8 b = *(const f16x8*)&WdB[(t * 64 + lane) * 8];
        f32x4 zero = (f32x4){0.f, 0.f, 0.f, 0.f};
        hb[t] = __builtin_amdgcn_mfma_f32_16x16x32_f16(a2, b, zero, 0, 0, 0);
    }
#pragma unroll
    for (int t = 0; t < 4; t++) {
        float bf = bds[16 * t + m];
#pragma unroll
        for (int r = 0; r < 4; r++) {
            int node = 16 * w + 4 * q + r;
            if (row0 + node < n)
                hd_ws[(size_t)(row0 + node) * 64 + 16 * t + m] = (f16)fmaxf(hb[t][r] + bf, 0.f);
        }
    }

    if (tid < 64) {
        int node = tid;
        float pa = bcs[0], pb = bcs[1], pc = bcs[2];
        for (int k = 0; k < 32; k++) {
            float zv = (float)Zh[node * 40 + k];
            pa += zv * Wcs[k * 4 + 0];
            pb += zv * Wcs[k * 4 + 1];
            pc += zv * Wcs[k * 4 + 2];
        }
        if (row0 + node < n) {
            pred_out[(size_t)(row0 + node) * 3 + 0] = pa;
            pred_out[(size_t)(row0 + node) * 3 + 1] = pb;
            pred_out[(size_t)(row0 + node) * 3 + 2] = pc;
        }
    }
}

// ---------------- GEMM5 (MFMA): x_recon[n,256] = p2[n,64] @ W_dec_gnn[64,256] + b ---------

#define G5_R 64
__global__ __launch_bounds__(256) void k_gemm5(const f16* __restrict__ A,
                                               const float* __restrict__ W,
                                               const float* __restrict__ bias,
                                               float* __restrict__ out, int n) {
    __shared__ __attribute__((aligned(16))) f16 WB[16 * 2 * 64 * 8];  // 32 KB
    __shared__ __attribute__((aligned(16))) f16 Ah[64 * 72];          // 9 KB
    __shared__ float bs[256];
    int tid = threadIdx.x;
    int row0 = blockIdx.x * G5_R;

    for (int i = tid; i < 4096; i += 256) {
        int k = i >> 6, c4 = (i & 63) * 4;
        float4 w = *(const float4*)&W[k * 256 + c4];
        int ks = k >> 5, q = (k >> 3) & 3, j = k & 7;
        int t = c4 >> 4;
        int base = ((t * 2 + ks) * 64 + q * 16 + (c4 & 15)) * 8 + j;
        WB[base + 0]  = (f16)w.x;
        WB[base + 8]  = (f16)w.y;
        WB[base + 16] = (f16)w.z;
        WB[base + 24] = (f16)w.w;
    }
    for (int i = tid; i < 1024; i += 256) {
        int r = i >> 4, c4 = (i & 15) * 4;
        half4 hv = {0, 0, 0, 0};
        if (row0 + r < n) hv = *(const half4*)&A[(size_t)(row0 + r) * 64 + c4];
        *(half4*)&Ah[r * 72 + c4] = hv;
    }
    bs[tid] = bias[tid];
    __syncthreads();

    int lane = tid & 63, w = tid >> 6;
    int m = lane & 15, q = lane >> 4;

    f16x8 a0 = *(const f16x8*)&Ah[(16 * w + m) * 72 + 0 + 8 * q];
    f16x8 a1 = *(const f16x8*)&Ah[(16 * w + m) * 72 + 32 + 8 * q];

    int gr0 = row0 + 16 * w + 4 * q;
    bool full = (gr0 + 3 < n);
#pragma unroll 4
    for (int t = 0; t < 16; t++) {
        f32x4 acc = (f32x4){0.f, 0.f, 0.f, 0.f};
        f16x8 b0 = *(const f16x8*)&WB[((t * 2 + 0) * 64 + lane) * 8];
        acc = __builtin_amdgcn_mfma_f32_16x16x32_f16(a0, b0, acc, 0, 0, 0);
        f16x8 b1 = *(const f16x8*)&WB[((t * 2 + 1) * 64 + lane) * 8];
        acc = __builtin_amdgcn_mfma_f32_16x16x32_f16(a1, b1, acc, 0, 0, 0);
        float bf = bs[16 * t + m];
        if (full) {
#pragma unroll
            for (int r = 0; r < 4; r++)
                out[(size_t)(gr0 + r) * 256 + 16 * t + m] = acc[r] + bf;
        } else {
#pragma unroll
            for (int r = 0; r < 4; r++)
                if (gr0 + r < n) out[(size_t)(gr0 + r) * 256 + 16 * t + m] = acc[r] + bf;
        }
    }
}

// ---------------- launch ----------------

extern "C" void kernel_launch(void* const* d_in, const int* in_sizes, int n_in,
                              void* d_out, int out_size, void* d_ws, size_t ws_size,
                              hipStream_t stream) {
    const float* x    = (const float*)d_in[0];
    const int*   ei   = (const int*)d_in[1];
    const float* Wenc = (const float*)d_in[3];
    const float* benc = (const float*)d_in[4];
    const float* Wz   = (const float*)d_in[5];
    const float* bz   = (const float*)d_in[6];
    const float* Wd   = (const float*)d_in[7];
    const float* bd   = (const float*)d_in[8];
    const float* Wdec = (const float*)d_in[9];
    const float* bdec = (const float*)d_in[10];
    const float* Wc   = (const float*)d_in[11];
    const float* bc   = (const float*)d_in[12];

    int n = in_sizes[0] / 256;
    int E = in_sizes[1] / 2;
    const int* src = ei;
    const int* dst = ei + E;

    int nbk = (n + BKT_SZ - 1) >> BKT_SH;
    int nbin = (E + EB - 1) / EB;

    char* w = (char*)d_ws;
    size_t off = 0;
    auto alloc = [&](size_t bytes) {
        void* p = w + off;
        off = (off + bytes + 255) & ~(size_t)255;
        return p;
    };
    int*      row_ptr = (int*)alloc(sizeof(int) * (n + 1));
    int*      ssorted = (int*)alloc(sizeof(int) * E);
    unsigned* ebuf    = (unsigned*)alloc(sizeof(unsigned) * E);
    float*    dinv    = (float*)alloc(sizeof(float) * n);
    int*      cnts    = (int*)alloc(sizeof(int) * 256);  // gcnt[128] + bcur[128]
    f16*      bufA    = (f16*)alloc(sizeof(f16) * (size_t)n * 64);  // h1pre -> hd
    f16*      bufB    = (f16*)alloc(sizeof(f16) * (size_t)n * 64);  // h1 -> p2
    (void)ws_size; (void)n_in; (void)out_size;

    int* gcnt = cnts;
    int* bcur = cnts + 128;

    float* out_xr = (float*)d_out;
    float* out_z  = out_xr + (size_t)n * 256;
    float* out_p  = out_z + (size_t)n * 32;

    // CSR build (bucketed counting sort) — 4 dispatches
    k_zero_int<<<dim3(1), dim3(256), 0, stream>>>(cnts, 256);
    k_bhist<<<dim3(nbin), dim3(256), 0, stream>>>(dst, E, nbk, gcnt);
    k_binA2<<<dim3(nbin), dim3(256), 0, stream>>>(src, dst, E, gcnt, bcur, ebuf);
    k_csr2<<<dim3(nbk), dim3(256), 0, stream>>>(ebuf, gcnt, n, E, row_ptr, dinv, ssorted);

    // encoder: bufA = x @ W_enc (f16) ; bufB = relu(P bufA + b_enc) (f16)
    k_gemm1<<<dim3((n + G1M_R - 1) / G1M_R), dim3(256), 0, stream>>>(x, Wenc, bufA, n);
    k_prop<true><<<dim3((n + 3) / 4), dim3(256), 0, stream>>>(bufA, row_ptr, ssorted, dinv, benc, bufB, n);

    // middle: z (out), pred (out), hd -> bufA (f16)
    k_mid<<<dim3((n + MB - 1) / MB), dim3(256), 0, stream>>>(bufB, Wz, bz, Wd, bd, Wc, bc,
                                                             bufA, out_z, out_p, n);

    // decoder (reassociated): bufB = P bufA (f16) ; x_recon = bufB @ W_dec + b_dec
    k_prop<false><<<dim3((n + 3) / 4), dim3(256), 0, stream>>>(bufA, row_ptr, ssorted, dinv, benc, bufB, n);
    k_gemm5<<<dim3((n + G5_R - 1) / G5_R), dim3(256), 0, stream>>>(bufB, Wdec, bdec, out_xr, n);
}

// Round 4
// 266.896 us; speedup vs baseline: 1.2984x; 1.0303x over previous
//
#include <hip/hip_runtime.h>
#include <stdint.h>

typedef _Float16 f16;
typedef _Float16 half4 __attribute__((ext_vector_type(4)));
typedef _Float16 f16x8 __attribute__((ext_vector_type(8)));
typedef float f32x4 __attribute__((ext_vector_type(4)));

// ---------------- shared-memory union for the fused CSR+GEMM1 phase kernels ----------

#define BKT_SH 9
#define BKT_SZ 512
#define EB 4096

struct __attribute__((aligned(16))) G1S { f16 WB[4 * 8 * 64 * 8]; f16 Ah[64 * 136]; };  // 49 KB
struct BinS { int h[128], segs[128], cur[128], s[256]; };
struct CsrS { int cnt[BKT_SZ], exc[BKT_SZ], cur2[BKT_SZ], p[256]; };
union __attribute__((aligned(16))) SmemU { G1S g1; BinS bin; CsrS csr; int bh[128]; };

// ---------------- device bodies ----------------

__device__ __forceinline__ void dev_bhist(SmemU& sm, const int* __restrict__ dst, int E, int nbk,
                                          int* __restrict__ gcnt, int bid) {
    int* h = sm.bh;
    int tid = threadIdx.x;
    if (tid < 128) h[tid] = 0;
    __syncthreads();
    int base = bid * EB;
    int end = min(base + EB, E);
    for (int i = base + tid; i < end; i += 256) atomicAdd(&h[dst[i] >> BKT_SH], 1);
    __syncthreads();
    if (tid < nbk && h[tid]) atomicAdd(&gcnt[tid], h[tid]);
}

__device__ __forceinline__ void dev_binA(SmemU& sm, const int* __restrict__ src,
                                         const int* __restrict__ dst, int E,
                                         const int* __restrict__ gcnt, int* __restrict__ bcur,
                                         unsigned* __restrict__ ebuf, int bid) {
    int* h = sm.bin.h; int* segs = sm.bin.segs; int* cur = sm.bin.cur; int* s = sm.bin.s;
    int tid = threadIdx.x;
    if (tid < 128) { h[tid] = 0; cur[tid] = 0; }
    __syncthreads();
    int base = bid * EB;
    int end = min(base + EB, E);
    for (int i = base + tid; i < end; i += 256) atomicAdd(&h[dst[i] >> BKT_SH], 1);
    int v = (tid < 128) ? gcnt[tid] : 0;
    s[tid] = v;
    __syncthreads();
    for (int o = 1; o < 256; o <<= 1) {
        int t = (tid >= o) ? s[tid - o] : 0;
        __syncthreads();
        s[tid] += t;
        __syncthreads();
    }
    if (tid < 128) segs[tid] = h[tid] ? (s[tid] - v) + atomicAdd(&bcur[tid], h[tid]) : 0;
    __syncthreads();
    for (int i = base + tid; i < end; i += 256) {
        int d = dst[i];
        int bk = d >> BKT_SH;
        int r = atomicAdd(&cur[bk], 1);
        ebuf[segs[bk] + r] = (unsigned)src[i] | ((unsigned)(d & (BKT_SZ - 1)) << 17);
    }
}

__device__ __forceinline__ void dev_csr(SmemU& sm, const unsigned* __restrict__ ebuf,
                                        const int* __restrict__ gcnt, int n, int E,
                                        int* __restrict__ row_ptr, float* __restrict__ dinv,
                                        int* __restrict__ ssorted, int b) {
    int* cnt = sm.csr.cnt; int* exc = sm.csr.exc; int* cur2 = sm.csr.cur2; int* p = sm.csr.p;
    int tid = threadIdx.x;
    int v = (tid < 128) ? gcnt[tid] : 0;
    p[tid] = v;
    __syncthreads();
    for (int o = 1; o < 256; o <<= 1) {
        int t = (tid >= o) ? p[tid - o] : 0;
        __syncthreads();
        p[tid] += t;
        __syncthreads();
    }
    int scnt = gcnt[b];
    int s0 = p[b] - scnt;
    __syncthreads();
    if (b == 0 && tid == 0) row_ptr[n] = E;

    int d0 = b << BKT_SH;
    int ndl = min(BKT_SZ, n - d0);
    cnt[tid] = 0; cnt[tid + 256] = 0;
    cur2[tid] = 0; cur2[tid + 256] = 0;
    __syncthreads();
    for (int i = tid; i < scnt; i += 256)
        atomicAdd(&cnt[(ebuf[s0 + i] >> 17) & (BKT_SZ - 1)], 1);
    __syncthreads();
    int a = cnt[2 * tid], c2 = cnt[2 * tid + 1];
    p[tid] = a + c2;
    __syncthreads();
    for (int o = 1; o < 256; o <<= 1) {
        int t = (tid >= o) ? p[tid - o] : 0;
        __syncthreads();
        p[tid] += t;
        __syncthreads();
    }
    int pex = p[tid] - (a + c2);
    exc[2 * tid] = pex;
    exc[2 * tid + 1] = pex + a;
    __syncthreads();
    for (int dl = tid; dl < ndl; dl += 256) {
        row_ptr[d0 + dl] = s0 + exc[dl];
        dinv[d0 + dl] = rsqrtf((float)(cnt[dl] + 1));  // +1 self loop
    }
    for (int i = tid; i < scnt; i += 256) {
        unsigned e = ebuf[s0 + i];
        int dl = (e >> 17) & (BKT_SZ - 1);
        int r = atomicAdd(&cur2[dl], 1);
        ssorted[s0 + exc[dl] + r] = (int)(e & 0x1FFFF);
    }
}

// GEMM1 body: h1_pre[64 rows of tile][64] = x[.,256] @ W[256,64] -> f16
__device__ __forceinline__ void dev_gemm1(SmemU& sm, const float* __restrict__ x,
                                          const float* __restrict__ W, f16* __restrict__ out,
                                          int n, int tile) {
    f16* WB = sm.g1.WB;
    f16* Ah = sm.g1.Ah;
    int tid = threadIdx.x;
    int row0 = tile * 64;

    for (int i = tid; i < 4096; i += 256) {
        int k = i >> 4, c4 = (i & 15) * 4;
        float4 w = *(const float4*)&W[k * 64 + c4];
        int t = c4 >> 4, ks = k >> 5, q = (k & 31) >> 3, j = k & 7;
        int base = (((t * 8 + ks) * 64 + q * 16 + (c4 & 15)) * 8) + j;
        WB[base + 0]  = (f16)w.x;
        WB[base + 8]  = (f16)w.y;
        WB[base + 16] = (f16)w.z;
        WB[base + 24] = (f16)w.w;
    }

    int lane = tid & 63, w = tid >> 6;
    int m = lane & 15, q = lane >> 4;

    f32x4 acc[4];
#pragma unroll
    for (int t = 0; t < 4; t++) acc[t] = (f32x4){0.f, 0.f, 0.f, 0.f};

    for (int h = 0; h < 2; h++) {
        __syncthreads();
        for (int i = tid; i < 2048; i += 256) {
            int r = i >> 5, k4 = (i & 31) * 4;
            float4 v = {0.f, 0.f, 0.f, 0.f};
            if (row0 + r < n) v = *(const float4*)&x[(size_t)(row0 + r) * 256 + 128 * h + k4];
            half4 hv;
            hv.x = (f16)v.x; hv.y = (f16)v.y; hv.z = (f16)v.z; hv.w = (f16)v.w;
            *(half4*)&Ah[r * 136 + k4] = hv;
        }
        __syncthreads();
#pragma unroll
        for (int ksl = 0; ksl < 4; ksl++) {
            int ks = 4 * h + ksl;
            f16x8 a = *(const f16x8*)&Ah[(16 * w + m) * 136 + 32 * ksl + 8 * q];
#pragma unroll
            for (int t = 0; t < 4; t++) {
                f16x8 b = *(const f16x8*)&WB[((t * 8 + ks) * 64 + lane) * 8];
                acc[t] = __builtin_amdgcn_mfma_f32_16x16x32_f16(a, b, acc[t], 0, 0, 0);
            }
        }
    }

#pragma unroll
    for (int t = 0; t < 4; t++) {
#pragma unroll
        for (int r = 0; r < 4; r++) {
            int gr = row0 + 16 * w + 4 * q + r;
            if (gr < n) out[(size_t)gr * 64 + 16 * t + m] = (f16)acc[t][r];
        }
    }
}

// ---------------- fused phase kernels: CSR stage (blocks [0,nA)) + gemm1 slice ---------

__global__ __launch_bounds__(256) void k_p1(const int* __restrict__ dst, int E, int nbk,
                                            int* __restrict__ gcnt,
                                            const float* __restrict__ x, const float* __restrict__ W,
                                            f16* __restrict__ out, int n, int nA, int tile0) {
    __shared__ SmemU sm;
    if ((int)blockIdx.x < nA) dev_bhist(sm, dst, E, nbk, gcnt, blockIdx.x);
    else dev_gemm1(sm, x, W, out, n, tile0 + (int)blockIdx.x - nA);
}

__global__ __launch_bounds__(256) void k_p2(const int* __restrict__ src, const int* __restrict__ dst,
                                            int E, const int* __restrict__ gcnt, int* __restrict__ bcur,
                                            unsigned* __restrict__ ebuf,
                                            const float* __restrict__ x, const float* __restrict__ W,
                                            f16* __restrict__ out, int n, int nA, int tile0) {
    __shared__ SmemU sm;
    if ((int)blockIdx.x < nA) dev_binA(sm, src, dst, E, gcnt, bcur, ebuf, blockIdx.x);
    else dev_gemm1(sm, x, W, out, n, tile0 + (int)blockIdx.x - nA);
}

__global__ __launch_bounds__(256) void k_p3(const unsigned* __restrict__ ebuf,
                                            const int* __restrict__ gcnt, int n, int E,
                                            int* __restrict__ row_ptr, float* __restrict__ dinv,
                                            int* __restrict__ ssorted,
                                            const float* __restrict__ x, const float* __restrict__ W,
                                            f16* __restrict__ out, int nA, int tile0) {
    __shared__ SmemU sm;
    if ((int)blockIdx.x < nA) dev_csr(sm, ebuf, gcnt, n, E, row_ptr, dinv, ssorted, blockIdx.x);
    else dev_gemm1(sm, x, W, out, n, tile0 + (int)blockIdx.x - nA);
}

// ---------------- propagation (f16 in/out): out[d] = dinv[d]*(sum dinv[s]*h[s] + dinv[d]*h[d])
// wave layout: 4 edge-subgroups (eg = lane>>4) x 16 feature-lanes (fg = lane&15).

template <bool RELU_BIAS>
__global__ __launch_bounds__(256) void k_prop(const f16* __restrict__ hpre,
                                              const int* __restrict__ row_ptr,
                                              const int* __restrict__ ssorted,
                                              const float* __restrict__ dinv,
                                              const float* __restrict__ bias,
                                              f16* __restrict__ out, int n) {
    int lane = threadIdx.x & 63, wid = threadIdx.x >> 6;
    int d = blockIdx.x * 4 + wid;
    if (d >= n) return;
    int fg = lane & 15;   // features 4*fg .. 4*fg+3
    int eg = lane >> 4;   // edge subgroup 0..3
    float dd = dinv[d];

    float ax = 0.f, ay = 0.f, az = 0.f, aw = 0.f;
    if (eg == 0) {  // self loop only in subgroup 0
        half4 hv = *(const half4*)&hpre[(size_t)d * 64 + 4 * fg];
        ax = dd * (float)hv.x; ay = dd * (float)hv.y;
        az = dd * (float)hv.z; aw = dd * (float)hv.w;
    }

    int s0 = row_ptr[d], s1 = row_ptr[d + 1];
    for (int base = s0; base < s1; base += 64) {
        int j = base + lane;
        int sl = 0;
        float wl = 0.f;
        if (j < s1) { sl = ssorted[j]; wl = dinv[sl]; }
        int cnt = min(64, s1 - base);
        int i = 0;
        for (; i + 8 <= cnt; i += 8) {  // 8 edges per iter, 2 independent loads/lane
            int e0 = i + eg, e1 = i + 4 + eg;
            int a0 = __shfl(sl, e0), a1 = __shfl(sl, e1);
            float w0 = __shfl(wl, e0), w1 = __shfl(wl, e1);
            half4 h0 = *(const half4*)&hpre[(size_t)a0 * 64 + 4 * fg];
            half4 h1 = *(const half4*)&hpre[(size_t)a1 * 64 + 4 * fg];
            ax += w0 * (float)h0.x; ay += w0 * (float)h0.y;
            az += w0 * (float)h0.z; aw += w0 * (float)h0.w;
            ax += w1 * (float)h1.x; ay += w1 * (float)h1.y;
            az += w1 * (float)h1.z; aw += w1 * (float)h1.w;
        }
        for (; i < cnt; i += 4) {  // tail: up to 4 edges, predicated
            int e = i + eg;
            int a = __shfl(sl, e);
            float w = __shfl(wl, e);
            if (e < cnt) {
                half4 hv = *(const half4*)&hpre[(size_t)a * 64 + 4 * fg];
                ax += w * (float)hv.x; ay += w * (float)hv.y;
                az += w * (float)hv.z; aw += w * (float)hv.w;
            }
        }
    }

    ax += __shfl_xor(ax, 16); ay += __shfl_xor(ay, 16);
    az += __shfl_xor(az, 16); aw += __shfl_xor(aw, 16);
    ax += __shfl_xor(ax, 32); ay += __shfl_xor(ay, 32);
    az += __shfl_xor(az, 32); aw += __shfl_xor(aw, 32);

    if (lane < 16) {
        float vx = dd * ax, vy = dd * ay, vz = dd * az, vw = dd * aw;
        if (RELU_BIAS) {
            float4 b = *(const float4*)&bias[4 * fg];
            vx = fmaxf(vx + b.x, 0.f); vy = fmaxf(vy + b.y, 0.f);
            vz = fmaxf(vz + b.z, 0.f); vw = fmaxf(vw + b.w, 0.f);
        }
        half4 hv;
        hv.x = (f16)vx; hv.y = (f16)vy; hv.z = (f16)vz; hv.w = (f16)vw;
        *(half4*)&out[(size_t)d * 64 + 4 * fg] = hv;
    }
}

// ---------------- fused middle (MFMA): 64 nodes per block; h1/hd are f16 ----------------

#define MB 64
__global__ __launch_bounds__(256) void k_mid(const f16* __restrict__ h1,
                                             const float* __restrict__ Wz, const float* __restrict__ bz,
                                             const float* __restrict__ Wd, const float* __restrict__ bd,
                                             const float* __restrict__ Wc, const float* __restrict__ bc,
                                             f16* __restrict__ hd_ws,
                                             float* __restrict__ z_out, float* __restrict__ pred_out,
                                             int n) {
    __shared__ __attribute__((aligned(16))) f16 Ah[64 * 72];
    __shared__ __attribute__((aligned(16))) f16 Zh[64 * 40];
    __shared__ __attribute__((aligned(16))) f16 WzB[2 * 2 * 64 * 8];
    __shared__ __attribute__((aligned(16))) f16 WdB[4 * 64 * 8];
    __shared__ float Wcs[32 * 4];
    __shared__ float bzs[32], bds[64], bcs[4];
    int tid = threadIdx.x;
    int row0 = blockIdx.x * MB;

    for (int i = tid; i < 2048; i += 256) {
        int k = i >> 5, c = i & 31;
        int ks = k >> 5, q = (k >> 3) & 3, j = k & 7;
        int t = c >> 4, ln = q * 16 + (c & 15);
        WzB[((t * 2 + ks) * 64 + ln) * 8 + j] = (f16)Wz[i];
    }
    for (int i = tid; i < 2048; i += 256) {
        int k = i >> 6, c = i & 63;
        int q = k >> 3, j = k & 7;
        int t = c >> 4, ln = q * 16 + (c & 15);
        WdB[(t * 64 + ln) * 8 + j] = (f16)Wd[i];
    }
    if (tid < 96) Wcs[(tid / 3) * 4 + (tid % 3)] = Wc[tid];
    if (tid < 32) bzs[tid] = bz[tid];
    if (tid < 64) bds[tid] = bd[tid];
    if (tid < 3)  bcs[tid] = bc[tid];
    for (int i = tid; i < 1024; i += 256) {
        int r = i >> 4, c4 = (i & 15) * 4;
        half4 hv = {0, 0, 0, 0};
        if (row0 + r < n) hv = *(const half4*)&h1[(size_t)(row0 + r) * 64 + c4];
        *(half4*)&Ah[r * 72 + c4] = hv;
    }
    __syncthreads();

    int lane = tid & 63, w = tid >> 6;
    int m = lane & 15, q = lane >> 4;

    f32x4 za[2];
    za[0] = (f32x4){0.f, 0.f, 0.f, 0.f};
    za[1] = (f32x4){0.f, 0.f, 0.f, 0.f};
#pragma unroll
    for (int ks = 0; ks < 2; ks++) {
        f16x8 a = *(const f16x8*)&Ah[(16 * w + m) * 72 + 32 * ks + 8 * q];
#pragma unroll
        for (int t = 0; t < 2; t++) {
            f16x8 b = *(const f16x8*)&WzB[((t * 2 + ks) * 64 + lane) * 8];
            za[t] = __builtin_amdgcn_mfma_f32_16x16x32_f16(a, b, za[t], 0, 0, 0);
        }
    }
#pragma unroll
    for (int t = 0; t < 2; t++) {
        float bj = bzs[16 * t + m];
#pragma unroll
        for (int r = 0; r < 4; r++) {
            int node = 16 * w + 4 * q + r;
            float zv = za[t][r] + bj;
            Zh[node * 40 + 16 * t + m] = (f16)zv;
            if (row0 + node < n) z_out[(size_t)(row0 + node) * 32 + 16 * t + m] = zv;
        }
    }
    __syncthreads();

    f16x8 a2 = *(const f16x8*)&Zh[(16 * w + m) * 40 + 8 * q];
    f32x4 hb[4];
#pragma unroll
    for (int t = 0; t < 4; t++) {
        f16x8 b = *(const f16x8*)&WdB[(t * 64 + lane) * 8];
        f32x4 zero = (f32x4){0.f, 0.f, 0.f, 0.f};
        hb[t] = __builtin_amdgcn_mfma_f32_16x16x32_f16(a2, b, zero, 0, 0, 0);
    }
#pragma unroll
    for (int t = 0; t < 4; t++) {
        float bf = bds[16 * t + m];
#pragma unroll
        for (int r = 0; r < 4; r++) {
            int node = 16 * w + 4 * q + r;
            if (row0 + node < n)
                hd_ws[(size_t)(row0 + node) * 64 + 16 * t + m] = (f16)fmaxf(hb[t][r] + bf, 0.f);
        }
    }

    if (tid < 64) {
        int node = tid;
        float pa = bcs[0], pb = bcs[1], pc = bcs[2];
        for (int k = 0; k < 32; k++) {
            float zv = (float)Zh[node * 40 + k];
            pa += zv * Wcs[k * 4 + 0];
            pb += zv * Wcs[k * 4 + 1];
            pc += zv * Wcs[k * 4 + 2];
        }
        if (row0 + node < n) {
            pred_out[(size_t)(row0 + node) * 3 + 0] = pa;
            pred_out[(size_t)(row0 + node) * 3 + 1] = pb;
            pred_out[(size_t)(row0 + node) * 3 + 2] = pc;
        }
    }
}

// ---------------- GEMM5 (MFMA): x_recon[n,256] = p2[n,64] @ W_dec_gnn[64,256] + b ---------

#define G5_R 64
__global__ __launch_bounds__(256) void k_gemm5(const f16* __restrict__ A,
                                               const float* __restrict__ W,
                                               const float* __restrict__ bias,
                                               float* __restrict__ out, int n) {
    __shared__ __attribute__((aligned(16))) f16 WB[16 * 2 * 64 * 8];  // 32 KB
    __shared__ __attribute__((aligned(16))) f16 Ah[64 * 72];          // 9 KB
    __shared__ float bs[256];
    int tid = threadIdx.x;
    int row0 = blockIdx.x * G5_R;

    for (int i = tid; i < 4096; i += 256) {
        int k = i >> 6, c4 = (i & 63) * 4;
        float4 w = *(const float4*)&W[k * 256 + c4];
        int ks = k >> 5, q = (k >> 3) & 3, j = k & 7;
        int t = c4 >> 4;
        int base = ((t * 2 + ks) * 64 + q * 16 + (c4 & 15)) * 8 + j;
        WB[base + 0]  = (f16)w.x;
        WB[base + 8]  = (f16)w.y;
        WB[base + 16] = (f16)w.z;
        WB[base + 24] = (f16)w.w;
    }
    for (int i = tid; i < 1024; i += 256) {
        int r = i >> 4, c4 = (i & 15) * 4;
        half4 hv = {0, 0, 0, 0};
        if (row0 + r < n) hv = *(const half4*)&A[(size_t)(row0 + r) * 64 + c4];
        *(half4*)&Ah[r * 72 + c4] = hv;
    }
    bs[tid] = bias[tid];
    __syncthreads();

    int lane = tid & 63, w = tid >> 6;
    int m = lane & 15, q = lane >> 4;

    f16x8 a0 = *(const f16x8*)&Ah[(16 * w + m) * 72 + 0 + 8 * q];
    f16x8 a1 = *(const f16x8*)&Ah[(16 * w + m) * 72 + 32 + 8 * q];

    int gr0 = row0 + 16 * w + 4 * q;
    bool full = (gr0 + 3 < n);
#pragma unroll 4
    for (int t = 0; t < 16; t++) {
        f32x4 acc = (f32x4){0.f, 0.f, 0.f, 0.f};
        f16x8 b0 = *(const f16x8*)&WB[((t * 2 + 0) * 64 + lane) * 8];
        acc = __builtin_amdgcn_mfma_f32_16x16x32_f16(a0, b0, acc, 0, 0, 0);
        f16x8 b1 = *(const f16x8*)&WB[((t * 2 + 1) * 64 + lane) * 8];
        acc = __builtin_amdgcn_mfma_f32_16x16x32_f16(a1, b1, acc, 0, 0, 0);
        float bf = bs[16 * t + m];
        if (full) {
#pragma unroll
            for (int r = 0; r < 4; r++)
                out[(size_t)(gr0 + r) * 256 + 16 * t + m] = acc[r] + bf;
        } else {
#pragma unroll
            for (int r = 0; r < 4; r++)
                if (gr0 + r < n) out[(size_t)(gr0 + r) * 256 + 16 * t + m] = acc[r] + bf;
        }
    }
}

// ---------------- launch ----------------

extern "C" void kernel_launch(void* const* d_in, const int* in_sizes, int n_in,
                              void* d_out, int out_size, void* d_ws, size_t ws_size,
                              hipStream_t stream) {
    const float* x    = (const float*)d_in[0];
    const int*   ei   = (const int*)d_in[1];
    const float* Wenc = (const float*)d_in[3];
    const float* benc = (const float*)d_in[4];
    const float* Wz   = (const float*)d_in[5];
    const float* bz   = (const float*)d_in[6];
    const float* Wd   = (const float*)d_in[7];
    const float* bd   = (const float*)d_in[8];
    const float* Wdec = (const float*)d_in[9];
    const float* bdec = (const float*)d_in[10];
    const float* Wc   = (const float*)d_in[11];
    const float* bc   = (const float*)d_in[12];

    int n = in_sizes[0] / 256;
    int E = in_sizes[1] / 2;
    const int* src = ei;
    const int* dst = ei + E;

    int nbk = (n + BKT_SZ - 1) >> BKT_SH;
    int nbin = (E + EB - 1) / EB;

    char* w = (char*)d_ws;
    size_t off = 0;
    auto alloc = [&](size_t bytes) {
        void* p = w + off;
        off = (off + bytes + 255) & ~(size_t)255;
        return p;
    };
    int*      row_ptr = (int*)alloc(sizeof(int) * (n + 1));
    int*      ssorted = (int*)alloc(sizeof(int) * E);
    unsigned* ebuf    = (unsigned*)alloc(sizeof(unsigned) * E);
    float*    dinv    = (float*)alloc(sizeof(float) * n);
    int*      cnts    = (int*)alloc(sizeof(int) * 256);  // gcnt[128] + bcur[128]
    f16*      bufA    = (f16*)alloc(sizeof(f16) * (size_t)n * 64);  // h1pre -> hd
    f16*      bufB    = (f16*)alloc(sizeof(f16) * (size_t)n * 64);  // h1 -> p2
    (void)ws_size; (void)n_in; (void)out_size;

    int* gcnt = cnts;
    int* bcur = cnts + 128;

    float* out_xr = (float*)d_out;
    float* out_z  = out_xr + (size_t)n * 256;
    float* out_p  = out_z + (size_t)n * 32;

    // gemm1 tile split across the three CSR phases
    int tiles = (n + 63) / 64;
    int t1 = tiles / 3;
    int t2 = (2 * tiles) / 3;

    hipMemsetAsync(cnts, 0, sizeof(int) * 256, stream);

    // phase 1: bhist || gemm1 tiles [0, t1)
    k_p1<<<dim3(nbin + t1), dim3(256), 0, stream>>>(dst, E, nbk, gcnt, x, Wenc, bufA, n, nbin, 0);
    // phase 2: binA || gemm1 tiles [t1, t2)
    k_p2<<<dim3(nbin + (t2 - t1)), dim3(256), 0, stream>>>(src, dst, E, gcnt, bcur, ebuf,
                                                           x, Wenc, bufA, n, nbin, t1);
    // phase 3: csr || gemm1 tiles [t2, tiles)
    k_p3<<<dim3(nbk + (tiles - t2)), dim3(256), 0, stream>>>(ebuf, gcnt, n, E, row_ptr, dinv, ssorted,
                                                             x, Wenc, bufA, nbk, t2);

    // encoder gather: bufB = relu(P bufA + b_enc) (f16)
    k_prop<true><<<dim3((n + 3) / 4), dim3(256), 0, stream>>>(bufA, row_ptr, ssorted, dinv, benc, bufB, n);

    // middle: z (out), pred (out), hd -> bufA (f16)
    k_mid<<<dim3((n + MB - 1) / MB), dim3(256), 0, stream>>>(bufB, Wz, bz, Wd, bd, Wc, bc,
                                                             bufA, out_z, out_p, n);

    // decoder (reassociated): bufB = P bufA (f16) ; x_recon = bufB @ W_dec + b_dec
    k_prop<false><<<dim3((n + 3) / 4), dim3(256), 0, stream>>>(bufA, row_ptr, ssorted, dinv, benc, bufB, n);
    k_gemm5<<<dim3((n + G5_R - 1) / G5_R), dim3(256), 0, stream>>>(bufB, Wdec, bdec, out_xr, n);
}